// Round 9
// baseline (152.198 us; speedup 1.0000x reference)
//
#include <hip/hip_runtime.h>
#include <math.h>

#define N_TOT 4096   // H*P*D
#define PHO_T 4096   // P*H*OUT_DIM
#define KTOT  40960  // 2*N + 8*N
#define NS    2560   // total k16 steps = KTOT/16
#define NSUP  16     // k-supers (partial slices)

typedef __attribute__((ext_vector_type(8)))  short short8v;  // 8 bf16 (4 VGPRs)
typedef __attribute__((ext_vector_type(16))) float f32x16;   // MFMA 32x32 acc

// global -> LDS direct DMA, 16 B per lane, dest = wave-uniform base + lane*16
#define GLD16(src, dst) __builtin_amdgcn_global_load_lds(                      \
    (const __attribute__((address_space(1))) void*)(src),                      \
    (__attribute__((address_space(3))) void*)(dst), 16, 0, 0)

// f32 -> (hi,lo) bf16, RNE on both (residual exact; dropped lo*lo term is
// zero-mean => no systematic bias in the GEMM)
__device__ __forceinline__ void split1(float x, short& h, short& l) {
    unsigned u  = __builtin_bit_cast(unsigned, x);
    unsigned hu = (u + 0x7FFFu + ((u >> 16) & 1u)) & 0xFFFF0000u;
    h = (short)(hu >> 16);
    float r = x - __builtin_bit_cast(float, hu);     // exact
    unsigned ur = __builtin_bit_cast(unsigned, r);
    l = (short)((ur + 0x7FFFu + ((ur >> 16) & 1u)) >> 16);
}

// ---------------------------------------------------------------------------
// Pass 1: A in MFMA-fragment order, hi/lo bf16 planes.
//   fragment stream: for k16-step S, plane p, lane l:
//     Af[((S*2+p)*64 + l)*8 + j] = Act_p[b = l&31][k = S*16 + (l>>5)*8 + j]
// ---------------------------------------------------------------------------
__global__ void act_kernel(const float* __restrict__ q,
                           const float* __restrict__ kx,
                           const float* __restrict__ grid_,
                           const float* __restrict__ coefq,
                           const float* __restrict__ coefk,
                           short* __restrict__ Af)
{
    const int t = blockIdx.x * 256 + threadIdx.x;  // 163840 = NS * 64
    const int S = t >> 6;
    const int l = t & 63;
    const int b = l & 31;
    const int k0 = S * 16 + (l >> 5) * 8;          // 8-aligned; never crosses a region

    float v[8];
    if (k0 < 8192) {
        const float* src = (k0 < 4096) ? (q  + (size_t)b * N_TOT + k0)
                                       : (kx + (size_t)b * N_TOT + (k0 - 4096));
#pragma unroll
        for (int j = 0; j < 8; ++j) {
            const float x = src[j];
            v[j] = x / (1.f + __expf(-x));
        }
    } else {
        const int f  = (k0 - 8192) >> 12;
        const int n0 = (k0 - 8192) & 4095;         // 8-aligned -> same group for all j
        const int g  = n0 >> 6;
        const float gf  = grid_[f];
        const float cq_ = coefq[g * 8 + f];
        const float ck_ = coefk[g * 8 + f];
        const float* qp = q  + (size_t)b * N_TOT + n0;
        const float* kp = kx + (size_t)b * N_TOT + n0;
#pragma unroll
        for (int j = 0; j < 8; ++j)
            v[j] = __sinf(gf * qp[j]) * cq_ + __sinf(gf * kp[j]) * ck_;
    }

    short8v hi, lo;
#pragma unroll
    for (int j = 0; j < 8; ++j) { short h, lw; split1(v[j], h, lw); hi[j] = h; lo[j] = lw; }
    *(short8v*)&Af[((size_t)(S * 2 + 0) * 64 + l) * 8] = hi;
    *(short8v*)&Af[((size_t)(S * 2 + 1) * 64 + l) * 8] = lo;
}

// ---------------------------------------------------------------------------
// Main GEMM via split-bf16 MFMA: ypart[ks][b][o] = sum_{k in super ks}
//   Act[k][b] * W[k][o]   (~ ah*wh + ah*wl + al*wh, 3x mfma_f32_32x32x16_bf16)
// KC=64: each weight row contributes a 256-B contiguous segment per chunk
// (vs 128 B in r6/r8) -> 2x DRAM row-buffer locality on the 16 KB-stride
// fetch stream, which is the hypothesized 25% BW loss.
// Grid: 16 K-supers (2560 k) x 32 o-blocks (128 o) = 512 blocks of 128 thr
// (2 waves) = 2 blocks/CU, one co-resident generation. Wave geometry = r6:
// each wave owns 64 o-rows -> two 32x32 MFMA tiles (r7 showed 1 tile/wave
// regresses). LDS 2buf x 128row x 256 B = 64 KB/block.
// BARRIER-FREE pipeline (LDS is wave-private), per-iteration issue order:
//   [8 Af loads (chunk c)] -> fence -> [16 DMA (chunk c+1)] -> vmcnt(16) -> compute
// vmcnt(16) retires chunk-c DMA + Af while chunk-c+1's 16 DMAs stay in
// flight across the whole compute phase (T3/T4: never drain to 0 in-loop).
// Chunks (64 k) are region-pure (64 | 4096): region resolved per chunk;
// conv chunks use separate accumulators, scaled by ss^2 in the epilogue.
// W f32 staged with XOR slot swizzle on BOTH sides (rule #21: 16 slots/row,
// XOR of low 3 slot bits keyed by row&7), converted to bf16 hi/lo in-reg.
// Epilogue: deterministic partial stores (no atomics).
// ---------------------------------------------------------------------------
#define OBK  128
#define KC   64
#define KSUP 2560
#define NCH  (KSUP / KC)   // 40 chunks per block

__global__ __launch_bounds__(128) void gemm_kernel(
    const float* __restrict__ bwq, const float* __restrict__ bwk,
    const float* __restrict__ cw,  const short* __restrict__ Af,
    const float* __restrict__ ssp, float* __restrict__ ypart)
{
    __shared__ float Wl[2][OBK * KC];   // 2 * 32 KB = 64 KB

    const int t  = threadIdx.x;
    const int ks = blockIdx.x >> 5;      // 0..15
    const int ob = blockIdx.x & 31;      // 0..31
    const int o_base = ob * OBK;
    const int k_base = ks * KSUP;

    const int w  = t >> 6;   // wave 0..1
    const int l  = t & 63;   // lane

    f32x16 accU0, accU1, accS0, accS1;
#pragma unroll
    for (int i = 0; i < 16; ++i) {
        accU0[i] = 0.f; accU1[i] = 0.f; accS0[i] = 0.f; accS1[i] = 0.f;
    }

    // weight row-pointer for global k index kg (chunk-uniform; includes the
    // k-column offset within the region)
    auto wptr = [&](int kg) -> const float* {
        if (kg < 4096)  return bwq + kg;
        if (kg < 8192)  return bwk + (kg - 4096);
        const int f    = (kg - 8192) >> 12;
        const int noff = (kg - 8192) & 4095;
        return cw + (size_t)f * (size_t)PHO_T * N_TOT + noff;
    };

    // stage the 64-k chunk at global k kg into buffer buf (16 DMA instrs/wave;
    // wave w writes rows w*64 .. w*64+63 only -> wave-private). One GLD16
    // covers 4 rows x 256 B; lane ln -> row +(ln>>4), slot (ln&15)^(row&7).
    auto stage = [&](int kg, int buf) {
        const float* Wp = wptr(kg);
#pragma unroll
        for (int i = 0; i < 16; ++i) {
            const int rb  = w * 64 + i * 4;          // row-group base (uniform)
            const int row = rb + (l >> 4);
            const int sslot = (l & 15) ^ (row & 7);  // XOR swizzle, low 3 bits
            const float* src = Wp + (size_t)(o_base + row) * N_TOT + sslot * 4;
            GLD16(src, &Wl[buf][rb * KC]);
        }
    };

    const int rkey = l & 7;              // row&7 for both tiles (row0&7 = l&7)
    const int row0 = w * 64 + (l & 31);
    const int j0b  = (l >> 5) * 2;

    // compute chunk (kg, buffer cur): 4 k16-steps x 2 tiles x 3 MFMA
    auto compute = [&](int kg, int cur, const short8v* ah, const short8v* al) {
        const bool sc = (kg >= 8192);    // conv region -> scaled accumulators
#pragma unroll
        for (int st = 0; st < 4; ++st) {
            const int j0 = st * 4 + j0b;             // logical f4 slot (0..15)

            auto tileop = [&](int nt, f32x16& acc) {
                const float* rp = &Wl[cur][(row0 + nt * 32) * KC];
                const float4 wa = *(const float4*)&rp[((j0    ) ^ rkey) * 4];
                const float4 wb = *(const float4*)&rp[((j0 + 1) ^ rkey) * 4];
                short8v bh, bl;
                {
                    short h, lw;
                    split1(wa.x, h, lw); bh[0] = h; bl[0] = lw;
                    split1(wa.y, h, lw); bh[1] = h; bl[1] = lw;
                    split1(wa.z, h, lw); bh[2] = h; bl[2] = lw;
                    split1(wa.w, h, lw); bh[3] = h; bl[3] = lw;
                    split1(wb.x, h, lw); bh[4] = h; bl[4] = lw;
                    split1(wb.y, h, lw); bh[5] = h; bl[5] = lw;
                    split1(wb.z, h, lw); bh[6] = h; bl[6] = lw;
                    split1(wb.w, h, lw); bh[7] = h; bl[7] = lw;
                }
                acc = __builtin_amdgcn_mfma_f32_32x32x16_bf16(ah[st], bh, acc, 0, 0, 0);
                acc = __builtin_amdgcn_mfma_f32_32x32x16_bf16(ah[st], bl, acc, 0, 0, 0);
                acc = __builtin_amdgcn_mfma_f32_32x32x16_bf16(al[st], bh, acc, 0, 0, 0);
            };
            if (sc) { tileop(0, accS0); tileop(1, accS1); }   // wave-uniform branch,
            else    { tileop(0, accU0); tileop(1, accU1); }   // static acc targets
        }
    };

    // prologue: chunk 0 DMA in flight (16 outstanding)
    stage(k_base, 0);

    short8v ah[4], al[4];
    for (int c = 0; c < NCH - 1; ++c) {
        const int cur = c & 1;
        const int kg  = k_base + c * KC;
        const size_t Sg = (size_t)(kg >> 4);
        // A fragments for chunk c (issued BEFORE next chunk's DMA)
#pragma unroll
        for (int st = 0; st < 4; ++st) {
            ah[st] = *(const short8v*)&Af[(((Sg + st) * 2 + 0) * 64 + l) * 8];
            al[st] = *(const short8v*)&Af[(((Sg + st) * 2 + 1) * 64 + l) * 8];
        }
        asm volatile("" ::: "memory");            // pin Af loads above the DMAs
        stage(kg + KC, cur ^ 1);                  // chunk c+1 DMA, stays in flight
        asm volatile("s_waitcnt vmcnt(16)" ::: "memory");  // chunk c + Af landed
        __builtin_amdgcn_sched_barrier(0);
        compute(kg, cur, ah, al);
    }
    {   // peeled last chunk: drain everything
        const int c   = NCH - 1;
        const int kg  = k_base + c * KC;
        const size_t Sg = (size_t)(kg >> 4);
#pragma unroll
        for (int st = 0; st < 4; ++st) {
            ah[st] = *(const short8v*)&Af[(((Sg + st) * 2 + 0) * 64 + l) * 8];
            al[st] = *(const short8v*)&Af[(((Sg + st) * 2 + 1) * 64 + l) * 8];
        }
        asm volatile("s_waitcnt vmcnt(0)" ::: "memory");
        __builtin_amdgcn_sched_barrier(0);
        compute(kg, c & 1, ah, al);
    }

    // epilogue: deterministic partial stores into this k-super's slice.
    // D layout (32x32): col = l&31, row(b) = (r&3) + 8*(r>>2) + 4*(l>>5)
    float* __restrict__ yp = ypart + (size_t)ks * (32 * PHO_T);
    const int o0 = o_base + w * 64 + (l & 31);
    const int o1 = o0 + 32;
    const float x0 = ssp[o0], x1 = ssp[o1];
    const float s0 = x0 * x0, s1 = x1 * x1;
    const int bh4 = 4 * (l >> 5);
#pragma unroll
    for (int r = 0; r < 16; ++r) {
        const int b = (r & 3) + 8 * (r >> 2) + bh4;
        yp[(size_t)b * PHO_T + o0] = accU0[r] + accS0[r] * s0;
        yp[(size_t)b * PHO_T + o1] = accU1[r] + accS1[r] * s1;
    }
}

// ---------------------------------------------------------------------------
// Reduce the 16 partial slices + bias term, then softmax over the last dim
// (32 contiguous elements per row). One 32-lane group per row; element
// index e = b*4096+o, so 32 consecutive threads = one softmax row.
// bias = 2*ss[o]^2 * sum_f cb[f][o].
// ---------------------------------------------------------------------------
__global__ void reduce_softmax_kernel(const float* __restrict__ ypart,
                                      const float* __restrict__ cb,
                                      const float* __restrict__ ssp,
                                      float* __restrict__ out)
{
    const int e = blockIdx.x * 256 + threadIdx.x;  // 131072 = 32*4096
    const int o = e & 4095;

    float v = 0.f;
#pragma unroll
    for (int ks = 0; ks < NSUP; ++ks)
        v += ypart[(size_t)ks * (32 * PHO_T) + e];

    float bias = 0.f;
#pragma unroll
    for (int f = 0; f < 8; ++f) bias += cb[f * PHO_T + o];
    const float ss = ssp[o];
    v += 2.f * ss * ss * bias;

    float m = v;
#pragma unroll
    for (int s = 16; s > 0; s >>= 1) m = fmaxf(m, __shfl_xor(m, s, 32));
    const float ex = __expf(v - m);
    float sum = ex;
#pragma unroll
    for (int s = 16; s > 0; s >>= 1) sum += __shfl_xor(sum, s, 32);
    out[e] = ex / sum;
}

// ---------------------------------------------------------------------------
extern "C" void kernel_launch(void* const* d_in, const int* in_sizes, int n_in,
                              void* d_out, int out_size, void* d_ws, size_t ws_size,
                              hipStream_t stream)
{
    const float* q    = (const float*)d_in[0];
    const float* k    = (const float*)d_in[1];
    const float* grid = (const float*)d_in[2];
    const float* bwq  = (const float*)d_in[3];
    const float* bwk  = (const float*)d_in[4];
    const float* cq   = (const float*)d_in[5];
    const float* ck   = (const float*)d_in[6];
    const float* cw   = (const float*)d_in[7];
    const float* cb   = (const float*)d_in[8];
    const float* ssp  = (const float*)d_in[9];
    float* out = (float*)d_out;

    short* Af    = (short*)d_ws;                                // NS*2*64*8 shorts = 5242880 B
    float* ypart = (float*)((char*)d_ws + (size_t)NS * 2 * 64 * 16);
    // ypart: NSUP * 131072 * 4 B = 8388608 B  (total ws use ~14 MB)

    act_kernel<<<640, 256, 0, stream>>>(q, k, grid, cq, ck, Af);
    gemm_kernel<<<512, 128, 0, stream>>>(bwq, bwk, cw, Af, ssp, ypart);
    reduce_softmax_kernel<<<512, 256, 0, stream>>>(ypart, cb, ssp, out);
}

// Round 10
// 145.152 us; speedup vs baseline: 1.0485x; 1.0485x over previous
//
#include <hip/hip_runtime.h>
#include <math.h>

#define N_TOT 4096   // H*P*D
#define PHO_T 4096   // P*H*OUT_DIM
#define KTOT  40960  // 2*N + 8*N
#define NS    2560   // total k16 steps = KTOT/16
#define NSUP  32     // k-supers (partial slices)

typedef __attribute__((ext_vector_type(8)))  short short8v;  // 8 bf16 (4 VGPRs)
typedef __attribute__((ext_vector_type(16))) float f32x16;   // MFMA 32x32 acc

// global -> LDS direct DMA, 16 B per lane, dest = wave-uniform base + lane*16
#define GLD16(src, dst) __builtin_amdgcn_global_load_lds(                      \
    (const __attribute__((address_space(1))) void*)(src),                      \
    (__attribute__((address_space(3))) void*)(dst), 16, 0, 0)

// f32 -> (hi,lo) bf16, RNE on both (residual exact; dropped lo*lo term is
// zero-mean => no systematic bias in the GEMM)
__device__ __forceinline__ void split1(float x, short& h, short& l) {
    unsigned u  = __builtin_bit_cast(unsigned, x);
    unsigned hu = (u + 0x7FFFu + ((u >> 16) & 1u)) & 0xFFFF0000u;
    h = (short)(hu >> 16);
    float r = x - __builtin_bit_cast(float, hu);     // exact
    unsigned ur = __builtin_bit_cast(unsigned, r);
    l = (short)((ur + 0x7FFFu + ((ur >> 16) & 1u)) >> 16);
}

// ---------------------------------------------------------------------------
// Pass 1: A in MFMA-fragment order, hi/lo bf16 planes.
//   fragment stream: for k16-step S, plane p, lane l:
//     Af[((S*2+p)*64 + l)*8 + j] = Act_p[b = l&31][k = S*16 + (l>>5)*8 + j]
// ---------------------------------------------------------------------------
__global__ void act_kernel(const float* __restrict__ q,
                           const float* __restrict__ kx,
                           const float* __restrict__ grid_,
                           const float* __restrict__ coefq,
                           const float* __restrict__ coefk,
                           short* __restrict__ Af)
{
    const int t = blockIdx.x * 256 + threadIdx.x;  // 163840 = NS * 64
    const int S = t >> 6;
    const int l = t & 63;
    const int b = l & 31;
    const int k0 = S * 16 + (l >> 5) * 8;          // 8-aligned; never crosses a region

    float v[8];
    if (k0 < 8192) {
        const float* src = (k0 < 4096) ? (q  + (size_t)b * N_TOT + k0)
                                       : (kx + (size_t)b * N_TOT + (k0 - 4096));
#pragma unroll
        for (int j = 0; j < 8; ++j) {
            const float x = src[j];
            v[j] = x / (1.f + __expf(-x));
        }
    } else {
        const int f  = (k0 - 8192) >> 12;
        const int n0 = (k0 - 8192) & 4095;         // 8-aligned -> same group for all j
        const int g  = n0 >> 6;
        const float gf  = grid_[f];
        const float cq_ = coefq[g * 8 + f];
        const float ck_ = coefk[g * 8 + f];
        const float* qp = q  + (size_t)b * N_TOT + n0;
        const float* kp = kx + (size_t)b * N_TOT + n0;
#pragma unroll
        for (int j = 0; j < 8; ++j)
            v[j] = __sinf(gf * qp[j]) * cq_ + __sinf(gf * kp[j]) * ck_;
    }

    short8v hi, lo;
#pragma unroll
    for (int j = 0; j < 8; ++j) { short h, lw; split1(v[j], h, lw); hi[j] = h; lo[j] = lw; }
    *(short8v*)&Af[((size_t)(S * 2 + 0) * 64 + l) * 8] = hi;
    *(short8v*)&Af[((size_t)(S * 2 + 1) * 64 + l) * 8] = lo;
}

// ---------------------------------------------------------------------------
// Main GEMM via split-bf16 MFMA: ypart[ks][b][o] = sum_{k in super ks}
//   Act[k][b] * W[k][o]   (~ ah*wh + ah*wl + al*wh, 3x mfma_f32_32x32x16_bf16)
// Geometry = r8 (proven local optimum, bracketed by r7/r9): 32 K-supers
// (1280 k) x 16 o-blocks (256 o) = 512 blocks x 4 waves = 2 blocks/CU,
// one co-resident generation. Wave owns 64 o-rows = two 32x32 tiles.
// NEW: half-chunk depth-2 pipeline. Each chunk (32 k) splits into two
// row-halves (= the two tiles, 4 DMAs of 1 KB each). Steady state per chunk:
//   [4 Af(c+1)] [D0(c+1)] vmcnt(12) comp(c,t0) [D1(c+1)] vmcnt(12) comp(c,t1)
// Each vmcnt(12) retires exactly the 4-op batch the next compute needs and
// keeps 12 ops (~12 KB/wave, 96 KB/CU) in flight -> finer-grained issue,
// deeper queue, no drain-to-0 in-loop (T3/T4). Af regs double-buffered via
// manually-unrolled body pairs (rule #20: no runtime-indexed reg arrays).
// BARRIER-FREE (LDS is wave-private). Chunks are region-pure (32 | 4096);
// conv chunks use separate accumulators, scaled by ss^2 in the epilogue.
// W f32 staged with XOR slot swizzle on BOTH sides (rule #21), converted to
// bf16 hi/lo in-register. Epilogue: deterministic partial stores.
// ---------------------------------------------------------------------------
#define OBK  256
#define KC   32
#define KSUP 1280
#define NCH  (KSUP / KC)   // 40 chunks per block (pipeline hardcodes 40 below)

__global__ __launch_bounds__(256) void gemm_kernel(
    const float* __restrict__ bwq, const float* __restrict__ bwk,
    const float* __restrict__ cw,  const short* __restrict__ Af,
    const float* __restrict__ ssp, float* __restrict__ ypart)
{
    __shared__ float Wl[2][OBK * KC];   // 2 * 32 KB

    const int t  = threadIdx.x;
    const int ks = blockIdx.x >> 4;      // 0..31
    const int ob = blockIdx.x & 15;      // 0..15
    const int o_base = ob * OBK;
    const int k_base = ks * KSUP;

    const int w  = t >> 6;   // wave 0..3
    const int l  = t & 63;   // lane
    const int srow  = l >> 3;
    const int sslot = (l & 7) ^ (srow & 7);   // DMA source swizzle (rule #21)

    f32x16 accU0, accU1, accS0, accS1;
#pragma unroll
    for (int i = 0; i < 16; ++i) {
        accU0[i] = 0.f; accU1[i] = 0.f; accS0[i] = 0.f; accS1[i] = 0.f;
    }

    // weight row-pointer for global k index kg (chunk-uniform)
    auto wptr = [&](int kg) -> const float* {
        if (kg < 4096)  return bwq + kg;
        if (kg < 8192)  return bwk + (kg - 4096);
        const int f    = (kg - 8192) >> 12;
        const int noff = (kg - 8192) & 4095;
        return cw + (size_t)f * (size_t)PHO_T * N_TOT + noff;
    };

    // stage HALF h (rows w*64+h*32 .. +32) of the chunk at kg into buffer buf:
    // 4 DMA instrs/wave, wave-private rows.
    auto stage_half = [&](int kg, int buf, int h) {
        const float* Wp = wptr(kg);
#pragma unroll
        for (int i = 0; i < 4; ++i) {
            const int rb  = w * 64 + h * 32 + i * 8;
            const int row = rb + srow;
            const float* src = Wp + (size_t)(o_base + row) * N_TOT + sslot * 4;
            GLD16(src, &Wl[buf][rb * KC]);
        }
    };

    const int rkey = l & 7;              // row&7 (w*64+h*32 = 0 mod 8)
    const int j0b  = (l >> 5) * 2;

    // compute tile h (rows w*64+h*32+..) of chunk (kg, buffer cur): 2 k16-steps
    auto compute_half = [&](int kg, int cur, int h,
                            const short8v& ah0, const short8v& al0,
                            const short8v& ah1, const short8v& al1,
                            f32x16& aU, f32x16& aS) {
        const bool sc = (kg >= 8192);    // conv region -> scaled accumulator
        const int rowh = w * 64 + h * 32 + (l & 31);
        const float* rp = &Wl[cur][rowh * KC];
#pragma unroll
        for (int s = 0; s < 2; ++s) {
            const short8v& ah = s ? ah1 : ah0;
            const short8v& al = s ? al1 : al0;
            const int j0 = s * 4 + j0b;
            const float4 wa = *(const float4*)&rp[((j0    ) ^ rkey) * 4];
            const float4 wb = *(const float4*)&rp[((j0 + 1) ^ rkey) * 4];
            short8v bh, bl;
            {
                short hh, lw;
                split1(wa.x, hh, lw); bh[0] = hh; bl[0] = lw;
                split1(wa.y, hh, lw); bh[1] = hh; bl[1] = lw;
                split1(wa.z, hh, lw); bh[2] = hh; bl[2] = lw;
                split1(wa.w, hh, lw); bh[3] = hh; bl[3] = lw;
                split1(wb.x, hh, lw); bh[4] = hh; bl[4] = lw;
                split1(wb.y, hh, lw); bh[5] = hh; bl[5] = lw;
                split1(wb.z, hh, lw); bh[6] = hh; bl[6] = lw;
                split1(wb.w, hh, lw); bh[7] = hh; bl[7] = lw;
            }
            f32x16& acc = sc ? aS : aU;            // wave-uniform select
            acc = __builtin_amdgcn_mfma_f32_32x32x16_bf16(ah, bh, acc, 0, 0, 0);
            acc = __builtin_amdgcn_mfma_f32_32x32x16_bf16(ah, bl, acc, 0, 0, 0);
            acc = __builtin_amdgcn_mfma_f32_32x32x16_bf16(al, bh, acc, 0, 0, 0);
        }
    };

#define LOAD_AF(Sg, H0, L0, H1, L1)                                            \
    H0 = *(const short8v*)&Af[(((Sg)     * 2 + 0) * 64 + l) * 8];              \
    L0 = *(const short8v*)&Af[(((Sg)     * 2 + 1) * 64 + l) * 8];              \
    H1 = *(const short8v*)&Af[(((Sg) + 1) * 2 + 0) * 64 * 8 + l * 8];          \
    L1 = *(const short8v*)&Af[((((Sg) + 1) * 2 + 1) * 64 + l) * 8];

    // (fix the H1 line to the same form as the others)
#undef LOAD_AF
#define LOAD_AF(Sg, H0, L0, H1, L1)                                            \
    H0 = *(const short8v*)&Af[(((Sg)      * 2 + 0) * 64 + l) * 8];             \
    L0 = *(const short8v*)&Af[(((Sg)      * 2 + 1) * 64 + l) * 8];             \
    H1 = *(const short8v*)&Af[((((Sg) + 1) * 2 + 0) * 64 + l) * 8];            \
    L1 = *(const short8v*)&Af[((((Sg) + 1) * 2 + 1) * 64 + l) * 8];

    // One pipeline body: compute chunk c with CUR regs, prefetch chunk c+1
    // (Af -> NXT regs, weights -> other LDS buffer, two half-batches).
#define BODY(c, CH0, CL0, CH1, CL1, NH0, NL0, NH1, NL1) do {                   \
    const int kg = k_base + (c) * KC;                                          \
    const size_t Sg2 = (size_t)((kg + KC) >> 4);                               \
    LOAD_AF(Sg2, NH0, NL0, NH1, NL1)                                           \
    asm volatile("" ::: "memory");          /* pin Af loads above the DMAs */  \
    stage_half(kg + KC, ((c) + 1) & 1, 0);                                     \
    asm volatile("s_waitcnt vmcnt(12)" ::: "memory");                          \
    __builtin_amdgcn_sched_barrier(0);                                         \
    compute_half(kg, (c) & 1, 0, CH0, CL0, CH1, CL1, accU0, accS0);            \
    stage_half(kg + KC, ((c) + 1) & 1, 1);                                     \
    asm volatile("s_waitcnt vmcnt(12)" ::: "memory");                          \
    __builtin_amdgcn_sched_barrier(0);                                         \
    compute_half(kg, (c) & 1, 1, CH0, CL0, CH1, CL1, accU1, accS1);            \
} while (0)

    short8v a_h0, a_l0, a_h1, a_l1;   // Af set A
    short8v b_h0, b_l0, b_h1, b_l1;   // Af set B

    // prologue: Af(0) -> set A, chunk 0 weights in flight (12 ops outstanding)
    {
        const size_t Sg = (size_t)(k_base >> 4);
        LOAD_AF(Sg, a_h0, a_l0, a_h1, a_l1)
        asm volatile("" ::: "memory");
        stage_half(k_base, 0, 0);
        stage_half(k_base, 0, 1);
    }

    // bodies 0..37 as pairs (even c: CUR=A, odd c: CUR=B), then body 38
    for (int cc = 0; cc < 19; ++cc) {
        const int c = cc * 2;
        BODY(c,     a_h0, a_l0, a_h1, a_l1,  b_h0, b_l0, b_h1, b_l1);
        BODY(c + 1, b_h0, b_l0, b_h1, b_l1,  a_h0, a_l0, a_h1, a_l1);
    }
    BODY(38, a_h0, a_l0, a_h1, a_l1,  b_h0, b_l0, b_h1, b_l1);

    // tail: chunk 39 (CUR=B). Outstanding here: Af(39)+D0(39)+D1(39)=12.
    {
        const int kg = k_base + 39 * KC;
        asm volatile("s_waitcnt vmcnt(4)" ::: "memory");   // Af(39)+D0(39) done
        __builtin_amdgcn_sched_barrier(0);
        compute_half(kg, 1, 0, b_h0, b_l0, b_h1, b_l1, accU0, accS0);
        asm volatile("s_waitcnt vmcnt(0)" ::: "memory");   // D1(39) done
        __builtin_amdgcn_sched_barrier(0);
        compute_half(kg, 1, 1, b_h0, b_l0, b_h1, b_l1, accU1, accS1);
    }
#undef BODY
#undef LOAD_AF

    // epilogue: deterministic partial stores into this k-super's slice.
    // D layout (32x32): col = l&31, row(b) = (r&3) + 8*(r>>2) + 4*(l>>5)
    float* __restrict__ yp = ypart + (size_t)ks * (32 * PHO_T);
    const int o0 = o_base + w * 64 + (l & 31);
    const int o1 = o0 + 32;
    const float x0 = ssp[o0], x1 = ssp[o1];
    const float s0 = x0 * x0, s1 = x1 * x1;
    const int bh4 = 4 * (l >> 5);
#pragma unroll
    for (int r = 0; r < 16; ++r) {
        const int b = (r & 3) + 8 * (r >> 2) + bh4;
        yp[(size_t)b * PHO_T + o0] = accU0[r] + accS0[r] * s0;
        yp[(size_t)b * PHO_T + o1] = accU1[r] + accS1[r] * s1;
    }
}

// ---------------------------------------------------------------------------
// Reduce the 32 partial slices + bias term, then softmax over the last dim
// (32 contiguous elements per row). One 32-lane group per row; element
// index e = b*4096+o, so 32 consecutive threads = one softmax row.
// bias = 2*ss[o]^2 * sum_f cb[f][o].
// ---------------------------------------------------------------------------
__global__ void reduce_softmax_kernel(const float* __restrict__ ypart,
                                      const float* __restrict__ cb,
                                      const float* __restrict__ ssp,
                                      float* __restrict__ out)
{
    const int e = blockIdx.x * 256 + threadIdx.x;  // 131072 = 32*4096
    const int o = e & 4095;

    float v = 0.f;
#pragma unroll
    for (int ks = 0; ks < NSUP; ++ks)
        v += ypart[(size_t)ks * (32 * PHO_T) + e];

    float bias = 0.f;
#pragma unroll
    for (int f = 0; f < 8; ++f) bias += cb[f * PHO_T + o];
    const float ss = ssp[o];
    v += 2.f * ss * ss * bias;

    float m = v;
#pragma unroll
    for (int s = 16; s > 0; s >>= 1) m = fmaxf(m, __shfl_xor(m, s, 32));
    const float ex = __expf(v - m);
    float sum = ex;
#pragma unroll
    for (int s = 16; s > 0; s >>= 1) sum += __shfl_xor(sum, s, 32);
    out[e] = ex / sum;
}

// ---------------------------------------------------------------------------
extern "C" void kernel_launch(void* const* d_in, const int* in_sizes, int n_in,
                              void* d_out, int out_size, void* d_ws, size_t ws_size,
                              hipStream_t stream)
{
    const float* q    = (const float*)d_in[0];
    const float* k    = (const float*)d_in[1];
    const float* grid = (const float*)d_in[2];
    const float* bwq  = (const float*)d_in[3];
    const float* bwk  = (const float*)d_in[4];
    const float* cq   = (const float*)d_in[5];
    const float* ck   = (const float*)d_in[6];
    const float* cw   = (const float*)d_in[7];
    const float* cb   = (const float*)d_in[8];
    const float* ssp  = (const float*)d_in[9];
    float* out = (float*)d_out;

    short* Af    = (short*)d_ws;                                // NS*2*64*8 shorts = 5242880 B
    float* ypart = (float*)((char*)d_ws + (size_t)NS * 2 * 64 * 16);
    // ypart: NSUP * 131072 * 4 B = 16777216 B  (total ws use ~22 MB)

    act_kernel<<<640, 256, 0, stream>>>(q, k, grid, cq, ck, Af);
    gemm_kernel<<<512, 256, 0, stream>>>(bwq, bwk, cw, Af, ssp, ypart);
    reduce_softmax_kernel<<<512, 256, 0, stream>>>(ypart, cb, ssp, out);
}

// Round 11
// 141.268 us; speedup vs baseline: 1.0774x; 1.0275x over previous
//
#include <hip/hip_runtime.h>
#include <math.h>

#define N_TOT 4096   // H*P*D
#define PHO_T 4096   // P*H*OUT_DIM
#define KTOT  40960  // 2*N + 8*N
#define NS    2560   // total k16 steps = KTOT/16
#define NSUP  32     // k-supers (partial slices)

typedef __attribute__((ext_vector_type(8)))  short short8v;  // 8 bf16 (4 VGPRs)
typedef __attribute__((ext_vector_type(16))) float f32x16;   // MFMA 32x32 acc

// global -> LDS direct DMA, 16 B per lane, dest = wave-uniform base + lane*16
#define GLD16(src, dst) __builtin_amdgcn_global_load_lds(                      \
    (const __attribute__((address_space(1))) void*)(src),                      \
    (__attribute__((address_space(3))) void*)(dst), 16, 0, 0)

// f32 -> (hi,lo) bf16, RNE on both (residual exact; dropped lo*lo term is
// zero-mean => no systematic bias in the GEMM)
__device__ __forceinline__ void split1(float x, short& h, short& l) {
    unsigned u  = __builtin_bit_cast(unsigned, x);
    unsigned hu = (u + 0x7FFFu + ((u >> 16) & 1u)) & 0xFFFF0000u;
    h = (short)(hu >> 16);
    float r = x - __builtin_bit_cast(float, hu);     // exact
    unsigned ur = __builtin_bit_cast(unsigned, r);
    l = (short)((ur + 0x7FFFu + ((ur >> 16) & 1u)) >> 16);
}

// ---------------------------------------------------------------------------
// Pass 1: A in MFMA-fragment order, hi/lo bf16 planes.
//   fragment stream: for k16-step S, plane p, lane l:
//     Af[((S*2+p)*64 + l)*8 + j] = Act_p[b = l&31][k = S*16 + (l>>5)*8 + j]
// ---------------------------------------------------------------------------
__global__ void act_kernel(const float* __restrict__ q,
                           const float* __restrict__ kx,
                           const float* __restrict__ grid_,
                           const float* __restrict__ coefq,
                           const float* __restrict__ coefk,
                           short* __restrict__ Af)
{
    const int t = blockIdx.x * 256 + threadIdx.x;  // 163840 = NS * 64
    const int S = t >> 6;
    const int l = t & 63;
    const int b = l & 31;
    const int k0 = S * 16 + (l >> 5) * 8;          // 8-aligned; never crosses a region

    float v[8];
    if (k0 < 8192) {
        const float* src = (k0 < 4096) ? (q  + (size_t)b * N_TOT + k0)
                                       : (kx + (size_t)b * N_TOT + (k0 - 4096));
#pragma unroll
        for (int j = 0; j < 8; ++j) {
            const float x = src[j];
            v[j] = x / (1.f + __expf(-x));
        }
    } else {
        const int f  = (k0 - 8192) >> 12;
        const int n0 = (k0 - 8192) & 4095;         // 8-aligned -> same group for all j
        const int g  = n0 >> 6;
        const float gf  = grid_[f];
        const float cq_ = coefq[g * 8 + f];
        const float ck_ = coefk[g * 8 + f];
        const float* qp = q  + (size_t)b * N_TOT + n0;
        const float* kp = kx + (size_t)b * N_TOT + n0;
#pragma unroll
        for (int j = 0; j < 8; ++j)
            v[j] = __sinf(gf * qp[j]) * cq_ + __sinf(gf * kp[j]) * ck_;
    }

    short8v hi, lo;
#pragma unroll
    for (int j = 0; j < 8; ++j) { short h, lw; split1(v[j], h, lw); hi[j] = h; lo[j] = lw; }
    *(short8v*)&Af[((size_t)(S * 2 + 0) * 64 + l) * 8] = hi;
    *(short8v*)&Af[((size_t)(S * 2 + 1) * 64 + l) * 8] = lo;
}

// ---------------------------------------------------------------------------
// Main GEMM via split-bf16 MFMA: ypart[ks][b][o] = sum_{k in super ks}
//   Act[k][b] * W[k][o]   (~ ah*wh + ah*wl + al*wh, 3x mfma_f32_32x32x16_bf16)
// Geometry/pipeline = r8 (proven best): 32 K-supers (1280 k) x 16 o-blocks
// (256 o) = 512 blocks x 4 waves = 2/CU, one generation; barrier-free,
// whole-chunk vmcnt(8) (never 0 in-loop).
// NEW: per-o-block CHUNK-ORDER ROTATION, c = (c0+i) mod 40, c0 = (ob*5)%40.
// Rationale: the 128B-segment/16KB-stride fetch makes a chunk's channel
// index a function of its k-column only (row term = 0 mod interleave);
// unrotated, all blocks start at the same k-phase -> ~16/128 channels
// active at launch. ks spans multiples-of-8 channel offsets, ob*5 spans all
// residues mod 8 -> rotated, instantaneous coverage is the full channel set.
// Sum order over k changes only (fp add reorder, within threshold).
// Region resolved per chunk (region-pure, 32 | 4096); conv chunks use
// separate accumulators, scaled by ss^2 in the epilogue. W f32 staged with
// XOR slot swizzle on BOTH sides (rule #21), converted to bf16 hi/lo
// in-register. Epilogue: deterministic partial stores (no atomics).
// ---------------------------------------------------------------------------
#define OBK  256
#define KC   32
#define KSUP 1280
#define NCH  (KSUP / KC)   // 40 chunks per block

__global__ __launch_bounds__(256) void gemm_kernel(
    const float* __restrict__ bwq, const float* __restrict__ bwk,
    const float* __restrict__ cw,  const short* __restrict__ Af,
    const float* __restrict__ ssp, float* __restrict__ ypart)
{
    __shared__ float Wl[2][OBK * KC];   // 2 * 32 KB

    const int t  = threadIdx.x;
    const int ks = blockIdx.x >> 4;      // 0..31
    const int ob = blockIdx.x & 15;      // 0..15
    const int o_base = ob * OBK;
    const int k_base = ks * KSUP;

    const int w  = t >> 6;   // wave 0..3
    const int l  = t & 63;   // lane
    const int srow  = l >> 3;
    const int sslot = (l & 7) ^ (srow & 7);   // DMA source swizzle (rule #21)

    f32x16 accU0, accU1, accS0, accS1;
#pragma unroll
    for (int i = 0; i < 16; ++i) {
        accU0[i] = 0.f; accU1[i] = 0.f; accS0[i] = 0.f; accS1[i] = 0.f;
    }

    // weight row-pointer for global k index kg (chunk-uniform)
    auto wptr = [&](int kg) -> const float* {
        if (kg < 4096)  return bwq + kg;
        if (kg < 8192)  return bwk + (kg - 4096);
        const int f    = (kg - 8192) >> 12;
        const int noff = (kg - 8192) & 4095;
        return cw + (size_t)f * (size_t)PHO_T * N_TOT + noff;
    };

    // stage the 32-k chunk at global k kg into buffer buf (8 DMA instrs/wave;
    // wave w writes rows w*64 .. w*64+63 only -> wave-private)
    auto stage = [&](int kg, int buf) {
        const float* Wp = wptr(kg);
#pragma unroll
        for (int i = 0; i < 8; ++i) {
            const int row = w * 64 + i * 8 + srow;
            const float* src = Wp + (size_t)(o_base + row) * N_TOT + sslot * 4;
            GLD16(src, &Wl[buf][(w * 64 + i * 8) * KC]);
        }
    };

    const int rkey = l & 7;              // row&7 for both tiles (nt*32 = 0 mod 8)
    const int row0 = w * 64 + (l & 31);
    const int j0b  = (l >> 5) * 2;

    // compute chunk (kg, buffer cur) from LDS + prefetched A fragments
    auto compute = [&](int kg, int cur, const short8v& ah0, const short8v& al0,
                       const short8v& ah1, const short8v& al1) {
        const bool sc = (kg >= 8192);    // conv region -> scaled accumulators
#pragma unroll
        for (int s = 0; s < 2; ++s) {
            const short8v& ah = s ? ah1 : ah0;
            const short8v& al = s ? al1 : al0;
            const int j0 = s * 4 + j0b;

            auto tileop = [&](int nt, f32x16& acc) {
                const float* rp = &Wl[cur][(row0 + nt * 32) * KC];
                const float4 wa = *(const float4*)&rp[((j0    ) ^ rkey) * 4];
                const float4 wb = *(const float4*)&rp[((j0 + 1) ^ rkey) * 4];
                short8v bh, bl;
                {
                    short h, lw;
                    split1(wa.x, h, lw); bh[0] = h; bl[0] = lw;
                    split1(wa.y, h, lw); bh[1] = h; bl[1] = lw;
                    split1(wa.z, h, lw); bh[2] = h; bl[2] = lw;
                    split1(wa.w, h, lw); bh[3] = h; bl[3] = lw;
                    split1(wb.x, h, lw); bh[4] = h; bl[4] = lw;
                    split1(wb.y, h, lw); bh[5] = h; bl[5] = lw;
                    split1(wb.z, h, lw); bh[6] = h; bl[6] = lw;
                    split1(wb.w, h, lw); bh[7] = h; bl[7] = lw;
                }
                acc = __builtin_amdgcn_mfma_f32_32x32x16_bf16(ah, bh, acc, 0, 0, 0);
                acc = __builtin_amdgcn_mfma_f32_32x32x16_bf16(ah, bl, acc, 0, 0, 0);
                acc = __builtin_amdgcn_mfma_f32_32x32x16_bf16(al, bh, acc, 0, 0, 0);
            };
            if (sc) { tileop(0, accS0); tileop(1, accS1); }   // wave-uniform branch,
            else    { tileop(0, accU0); tileop(1, accU1); }   // static acc targets
        }
    };

    // chunk-order rotation: start at c0, wrap mod NCH
    const int c0 = (ob * 5) % NCH;
    int ci = c0;

    // prologue: chunk c0 DMA in flight
    stage(k_base + ci * KC, 0);

    short8v ah0, al0, ah1, al1;
    for (int i = 0; i < NCH - 1; ++i) {
        const int cur = i & 1;
        const int kg  = k_base + ci * KC;
        int cn = ci + 1; if (cn == NCH) cn = 0;
        const size_t Sg = (size_t)(kg >> 4);
        // A fragments for chunk ci (issued BEFORE next chunk's DMA)
        ah0 = *(const short8v*)&Af[(((Sg    ) * 2 + 0) * 64 + l) * 8];
        al0 = *(const short8v*)&Af[(((Sg    ) * 2 + 1) * 64 + l) * 8];
        ah1 = *(const short8v*)&Af[(((Sg + 1) * 2 + 0) * 64 + l) * 8];
        al1 = *(const short8v*)&Af[(((Sg + 1) * 2 + 1) * 64 + l) * 8];
        asm volatile("" ::: "memory");            // pin Af loads above the DMAs
        stage(k_base + cn * KC, cur ^ 1);         // next chunk DMA, stays in flight
        asm volatile("s_waitcnt vmcnt(8)" ::: "memory");  // chunk ci + Af landed
        __builtin_amdgcn_sched_barrier(0);
        compute(kg, cur, ah0, al0, ah1, al1);
        ci = cn;
    }
    {   // peeled last chunk (ci = (c0+NCH-1)%NCH, buffer (NCH-1)&1): drain all
        const int kg  = k_base + ci * KC;
        const size_t Sg = (size_t)(kg >> 4);
        ah0 = *(const short8v*)&Af[(((Sg    ) * 2 + 0) * 64 + l) * 8];
        al0 = *(const short8v*)&Af[(((Sg    ) * 2 + 1) * 64 + l) * 8];
        ah1 = *(const short8v*)&Af[(((Sg + 1) * 2 + 0) * 64 + l) * 8];
        al1 = *(const short8v*)&Af[(((Sg + 1) * 2 + 1) * 64 + l) * 8];
        asm volatile("s_waitcnt vmcnt(0)" ::: "memory");
        __builtin_amdgcn_sched_barrier(0);
        compute(kg, (NCH - 1) & 1, ah0, al0, ah1, al1);
    }

    // epilogue: deterministic partial stores into this k-super's slice.
    // D layout (32x32): col = l&31, row(b) = (r&3) + 8*(r>>2) + 4*(l>>5)
    float* __restrict__ yp = ypart + (size_t)ks * (32 * PHO_T);
    const int o0 = o_base + w * 64 + (l & 31);
    const int o1 = o0 + 32;
    const float x0 = ssp[o0], x1 = ssp[o1];
    const float s0 = x0 * x0, s1 = x1 * x1;
    const int bh4 = 4 * (l >> 5);
#pragma unroll
    for (int r = 0; r < 16; ++r) {
        const int b = (r & 3) + 8 * (r >> 2) + bh4;
        yp[(size_t)b * PHO_T + o0] = accU0[r] + accS0[r] * s0;
        yp[(size_t)b * PHO_T + o1] = accU1[r] + accS1[r] * s1;
    }
}

// ---------------------------------------------------------------------------
// Reduce the 32 partial slices + bias term, then softmax over the last dim
// (32 contiguous elements per row). One 32-lane group per row; element
// index e = b*4096+o, so 32 consecutive threads = one softmax row.
// bias = 2*ss[o]^2 * sum_f cb[f][o].
// ---------------------------------------------------------------------------
__global__ void reduce_softmax_kernel(const float* __restrict__ ypart,
                                      const float* __restrict__ cb,
                                      const float* __restrict__ ssp,
                                      float* __restrict__ out)
{
    const int e = blockIdx.x * 256 + threadIdx.x;  // 131072 = 32*4096
    const int o = e & 4095;

    float v = 0.f;
#pragma unroll
    for (int ks = 0; ks < NSUP; ++ks)
        v += ypart[(size_t)ks * (32 * PHO_T) + e];

    float bias = 0.f;
#pragma unroll
    for (int f = 0; f < 8; ++f) bias += cb[f * PHO_T + o];
    const float ss = ssp[o];
    v += 2.f * ss * ss * bias;

    float m = v;
#pragma unroll
    for (int s = 16; s > 0; s >>= 1) m = fmaxf(m, __shfl_xor(m, s, 32));
    const float ex = __expf(v - m);
    float sum = ex;
#pragma unroll
    for (int s = 16; s > 0; s >>= 1) sum += __shfl_xor(sum, s, 32);
    out[e] = ex / sum;
}

// ---------------------------------------------------------------------------
extern "C" void kernel_launch(void* const* d_in, const int* in_sizes, int n_in,
                              void* d_out, int out_size, void* d_ws, size_t ws_size,
                              hipStream_t stream)
{
    const float* q    = (const float*)d_in[0];
    const float* k    = (const float*)d_in[1];
    const float* grid = (const float*)d_in[2];
    const float* bwq  = (const float*)d_in[3];
    const float* bwk  = (const float*)d_in[4];
    const float* cq   = (const float*)d_in[5];
    const float* ck   = (const float*)d_in[6];
    const float* cw   = (const float*)d_in[7];
    const float* cb   = (const float*)d_in[8];
    const float* ssp  = (const float*)d_in[9];
    float* out = (float*)d_out;

    short* Af    = (short*)d_ws;                                // NS*2*64*8 shorts = 5242880 B
    float* ypart = (float*)((char*)d_ws + (size_t)NS * 2 * 64 * 16);
    // ypart: NSUP * 131072 * 4 B = 16777216 B  (total ws use ~22 MB)

    act_kernel<<<640, 256, 0, stream>>>(q, k, grid, cq, ck, Af);
    gemm_kernel<<<512, 256, 0, stream>>>(bwq, bwk, cw, Af, ssp, ypart);
    reduce_softmax_kernel<<<512, 256, 0, stream>>>(ypart, cb, ssp, out);
}